// Round 9
// baseline (29279.913 us; speedup 1.0000x reference)
//
#include <hip/hip_runtime.h>
#include <stdint.h>

// =====================================================================
// DiffusionPolicy fused rollout (gfx950) — R8: switch RNG sampling to
// JAX *partitionable* threefry layout (default since jax 0.4.30):
//   bits[e] = o0 ^ o1 of threefry2x32(key, (hi32(e), lo32(e))=(0,e))
// (legacy layout paired e with e+size/2 and took o0/o1 per half — that
// is what R4-R7 implemented and KAT-verified against legacy anchors).
// Rollout mechanics identical to R6/R7 (full-f32 VALU, stable dynamics).
// Sentinels in out[0]: 100 = in_sizes/n_in mismatch, 50 = ws too small,
// 25 = out_size mismatch, 8 = threefry core KAT failure.
// =====================================================================

#define TSTEPS 100

// ---- workspace layout (bytes); total < 10 KB ----
#define OFF_SCHED  0u        // 100*6*4 = 2400
#define OFF_ZK     2432u     // 100*2*4 = 800
#define OFF_TE     3264u     // 100*16*4 = 6400
#define WS_NEED    9664u

// ---------------------------------------------------------------------
__device__ __forceinline__ void threefry2x32(uint32_t k0, uint32_t k1,
                                             uint32_t c0, uint32_t c1,
                                             uint32_t& o0, uint32_t& o1) {
  const uint32_t k2 = k0 ^ k1 ^ 0x1BD11BDAu;
  uint32_t x0 = c0 + k0;
  uint32_t x1 = c1 + k1;
#define TF_ROUND(r) { x0 += x1; x1 = (x1 << r) | (x1 >> (32 - r)); x1 ^= x0; }
  TF_ROUND(13) TF_ROUND(15) TF_ROUND(26) TF_ROUND(6)
  x0 += k1; x1 += k2 + 1u;
  TF_ROUND(17) TF_ROUND(29) TF_ROUND(16) TF_ROUND(24)
  x0 += k2; x1 += k0 + 2u;
  TF_ROUND(13) TF_ROUND(15) TF_ROUND(26) TF_ROUND(6)
  x0 += k0; x1 += k1 + 3u;
  TF_ROUND(17) TF_ROUND(29) TF_ROUND(16) TF_ROUND(24)
  x0 += k1; x1 += k2 + 4u;
  TF_ROUND(13) TF_ROUND(15) TF_ROUND(26) TF_ROUND(6)
  x0 += k2; x1 += k0 + 5u;
#undef TF_ROUND
  o0 = x0; o1 = x1;
}

// XLA ErfInv32 (Giles)
__device__ __forceinline__ float jax_erfinv(float x) {
  float w = -log1pf(-x * x);
  float p;
  if (w < 5.0f) {
    w -= 2.5f;
    p = 2.81022636e-08f;
    p = fmaf(p, w, 3.43273939e-07f);
    p = fmaf(p, w, -3.5233877e-06f);
    p = fmaf(p, w, -4.39150654e-06f);
    p = fmaf(p, w, 0.00021858087f);
    p = fmaf(p, w, -0.00125372503f);
    p = fmaf(p, w, -0.00417768164f);
    p = fmaf(p, w, 0.246640727f);
    p = fmaf(p, w, 1.50140941f);
  } else {
    w = sqrtf(w) - 3.0f;
    p = -0.000200214257f;
    p = fmaf(p, w, 0.000100950558f);
    p = fmaf(p, w, 0.00134934322f);
    p = fmaf(p, w, -0.00367342844f);
    p = fmaf(p, w, 0.00573950773f);
    p = fmaf(p, w, -0.0076224613f);
    p = fmaf(p, w, 0.00943887047f);
    p = fmaf(p, w, 1.00167406f);
    p = fmaf(p, w, 2.83297682f);
  }
  return p * x;
}

__device__ __forceinline__ float jax_normal(uint32_t bits) {
  const float LO = -0.99999994039535522461f;          // nextafter(-1,0)
  float f = __uint_as_float(0x3f800000u | (bits >> 9)) - 1.0f; // [0,1)
  float u = fmaxf(LO, fmaf(f, 2.0f, LO));             // hi-lo == 2.0f (RNE)
  return 1.41421356237f * jax_erfinv(u);
}

// PARTITIONABLE threefry random bits: element e (flat row-major index,
// e < 2^32) uses counter (0, e); 32-bit draw folds both cipher words.
__device__ __forceinline__ float z_for(uint32_t e, uint32_t k0, uint32_t k1) {
  uint32_t o0, o1;
  threefry2x32(k0, k1, 0u, e, o0, o1);
  return jax_normal(o0 ^ o1);
}

// accurate mish: x*tanh(softplus(x)) = x * u(u+2)/(u^2+2u+2), u=e^x
__device__ __forceinline__ float mish_acc(float v) {
  float u = expf(fminf(v, 30.0f));
  float n = u * (u + 2.0f);
  return v * (n / (n + 2.0f));
}
__device__ __forceinline__ float mish_ref(float s) {
  float sp = fmaxf(s, 0.0f) + log1pf(expf(-fabsf(s)));
  return s * tanhf(sp);
}

// ---------------------------------------------------------------------
// setup: schedule constants, fold_in keys, time embedding (f32 exact).
// fold_in(key, t) = threefry_2x32(key, threefry_seed(t)) -> counter
// (0, t) with key (0,42); unaffected by the partitionable flag.
// ---------------------------------------------------------------------
__global__ void setup_sched(const float* __restrict__ tw1, const float* __restrict__ tb1,
                            const float* __restrict__ tw2, const float* __restrict__ tb2,
                            float* __restrict__ sched, uint32_t* __restrict__ zk,
                            float* __restrict__ te_f)
{
  int t = threadIdx.x;
  if (t >= TSTEPS) return;
  const float step = (0.02f - 1e-4f) / 99.0f;
  float ac = 1.0f, acp = 1.0f, beta = 0.0f, alpha = 1.0f;
  for (int i = 0; i <= t; ++i) {
    beta  = 1e-4f + step * (float)i;
    alpha = 1.0f - beta;
    acp   = ac;
    ac    = ac * alpha;
  }
  float one_m = 1.0f - ac;
  sched[t*6+0] = sqrtf(1.0f / ac);                       // sqrt_recip_ac
  sched[t*6+1] = sqrtf(one_m / ac);                      // sqrt_recipm1_ac
  sched[t*6+2] = beta * sqrtf(acp) / one_m;              // coef_x0
  sched[t*6+3] = (1.0f - acp) * sqrtf(alpha) / one_m;    // coef_xt
  float sig = 0.0f;
  if (t > 0) {
    float pv = beta * (1.0f - acp) / one_m;
    sig = expf(0.5f * logf(fmaxf(pv, 1e-20f)));          // exp(0.5*log_var)
  }
  sched[t*6+4] = sig;
  sched[t*6+5] = 0.0f;

  uint32_t o0, o1;
  threefry2x32(0u, 42u, 0u, (uint32_t)t, o0, o1);        // fold_in(key(42), t)
  zk[t*2+0] = o0; zk[t*2+1] = o1;

  float te0[16];
  const float C = (float)(-9.210340371976184 / 7.0);     // -log(1e4)/(half-1)
  for (int i = 0; i < 8; ++i) {
    float ang = (float)t * expf((float)i * C);
    te0[i]   = sinf(ang);
    te0[i+8] = cosf(ang);
  }
  float h32[32];
  for (int j = 0; j < 32; ++j) {
    float s = tb1[j];
    for (int i = 0; i < 16; ++i) s += te0[i] * tw1[i*32 + j];
    h32[j] = mish_ref(s);
  }
  for (int j = 0; j < 16; ++j) {
    float s = tb2[j];
    for (int i = 0; i < 32; ++i) s += h32[i] * tw2[i*16 + j];
    te_f[t*16 + j] = s;                                  // full f32
  }
}

// ---------------------------------------------------------------------
// f32 GEMM fragment: 8 rows x 4 cols per thread over K, sequential in k.
// ---------------------------------------------------------------------
template<int K, int RS>
__device__ __forceinline__ void gemm_part(const float* __restrict__ src, int r0w,
                                          const float* __restrict__ W, int n4,
                                          float4 bv, float acc[8][4])
{
#pragma unroll
  for (int i = 0; i < 8; ++i) {
    acc[i][0] = bv.x; acc[i][1] = bv.y; acc[i][2] = bv.z; acc[i][3] = bv.w;
  }
  for (int k = 0; k < K; k += 4) {
    float4 w0 = *(const float4*)(W + (size_t)(k+0)*256 + n4);
    float4 w1 = *(const float4*)(W + (size_t)(k+1)*256 + n4);
    float4 w2 = *(const float4*)(W + (size_t)(k+2)*256 + n4);
    float4 w3 = *(const float4*)(W + (size_t)(k+3)*256 + n4);
#pragma unroll
    for (int i = 0; i < 8; ++i) {
      float4 h4 = *(const float4*)(src + (size_t)(r0w + i)*RS + k);
      acc[i][0] = fmaf(h4.x, w0.x, acc[i][0]);
      acc[i][0] = fmaf(h4.y, w1.x, acc[i][0]);
      acc[i][0] = fmaf(h4.z, w2.x, acc[i][0]);
      acc[i][0] = fmaf(h4.w, w3.x, acc[i][0]);
      acc[i][1] = fmaf(h4.x, w0.y, acc[i][1]);
      acc[i][1] = fmaf(h4.y, w1.y, acc[i][1]);
      acc[i][1] = fmaf(h4.z, w2.y, acc[i][1]);
      acc[i][1] = fmaf(h4.w, w3.y, acc[i][1]);
      acc[i][2] = fmaf(h4.x, w0.z, acc[i][2]);
      acc[i][2] = fmaf(h4.y, w1.z, acc[i][2]);
      acc[i][2] = fmaf(h4.z, w2.z, acc[i][2]);
      acc[i][2] = fmaf(h4.w, w3.z, acc[i][2]);
      acc[i][3] = fmaf(h4.x, w0.w, acc[i][3]);
      acc[i][3] = fmaf(h4.y, w1.w, acc[i][3]);
      acc[i][3] = fmaf(h4.z, w2.w, acc[i][3]);
      acc[i][3] = fmaf(h4.w, w3.w, acc[i][3]);
    }
  }
}

// ---------------------------------------------------------------------
// main persistent kernel: 2048 blocks x 256 threads, 32 rows/block.
// LDS: IN[32][96] f32 (x|state|te) + H[32][256] f32 -> 45 KB.
// ---------------------------------------------------------------------
__launch_bounds__(256, 3)
__global__ void diff_main(
    const float* __restrict__ w1, const float* __restrict__ w2,
    const float* __restrict__ w3, const float* __restrict__ w4,
    const float* __restrict__ b1, const float* __restrict__ b2,
    const float* __restrict__ b3, const float* __restrict__ bF,
    const float* __restrict__ stateF, const float* __restrict__ teF,
    const float* __restrict__ sched, const uint32_t* __restrict__ zkeys,
    int host_flag,
    float* __restrict__ out)
{
  __shared__ float IN[32][96];    // cols 0-15 x | 16-79 state | 80-95 te
  __shared__ float H[32][256];

  const int tid  = threadIdx.x;
  const int lane = tid & 63;
  const int wv   = tid >> 6;
  const int n4   = lane * 4;
  const int r0w  = wv * 8;
  const uint32_t gr0 = (uint32_t)blockIdx.x * 32u;

  const float4 b1v = *(const float4*)(b1 + n4);
  const float4 b2v = *(const float4*)(b2 + n4);
  const float4 b3v = *(const float4*)(b3 + n4);

  const int ur = tid >> 2;          // valid row for tid<128
  const int uc = (tid & 3) * 4;
  const float4 bFv = *(const float4*)(bF + uc);

  // ---- stage state (constant across steps) ----
  for (int q = tid; q < 512; q += 256) {
    int r = q >> 4, cc = (q & 15) * 4;
    *(float4*)&IN[r][16 + cc] =
        *(const float4*)(stateF + (size_t)(gr0 + (uint32_t)r) * 64u + (uint32_t)cc);
  }

  // ---- x init from key(7), partitionable layout ----
  float xr[4] = {0.f, 0.f, 0.f, 0.f};
  if (tid < 128) {
    uint32_t ebase = (gr0 + (uint32_t)ur) * 16u + (uint32_t)uc;
#pragma unroll
    for (int j = 0; j < 4; ++j) xr[j] = z_for(ebase + (uint32_t)j, 0u, 7u);
  }

  float acc[8][4];

  for (int t = TSTEPS - 1; t >= 0; --t) {
    __syncthreads();
    if (tid < 128) {
      float4 xv; xv.x = xr[0]; xv.y = xr[1]; xv.z = xr[2]; xv.w = xr[3];
      *(float4*)&IN[ur][uc] = xv;
      *(float4*)&IN[ur][80 + uc] = *(const float4*)(teF + t*16 + uc);
    }
    __syncthreads();

    // ---- L1: IN(96) -> H ----
    gemm_part<96, 96>(&IN[0][0], r0w, w1, n4, b1v, acc);
#pragma unroll
    for (int i = 0; i < 8; ++i) {
      float4 o;
      o.x = mish_acc(acc[i][0]); o.y = mish_acc(acc[i][1]);
      o.z = mish_acc(acc[i][2]); o.w = mish_acc(acc[i][3]);
      *(float4*)&H[r0w + i][n4] = o;
    }
    __syncthreads();

    // ---- L2 ----
    gemm_part<256, 256>(&H[0][0], r0w, w2, n4, b2v, acc);
    __syncthreads();
#pragma unroll
    for (int i = 0; i < 8; ++i) {
      float4 o;
      o.x = mish_acc(acc[i][0]); o.y = mish_acc(acc[i][1]);
      o.z = mish_acc(acc[i][2]); o.w = mish_acc(acc[i][3]);
      *(float4*)&H[r0w + i][n4] = o;
    }
    __syncthreads();

    // ---- L3 ----
    gemm_part<256, 256>(&H[0][0], r0w, w3, n4, b3v, acc);
    __syncthreads();
#pragma unroll
    for (int i = 0; i < 8; ++i) {
      float4 o;
      o.x = mish_acc(acc[i][0]); o.y = mish_acc(acc[i][1]);
      o.z = mish_acc(acc[i][2]); o.w = mish_acc(acc[i][3]);
      *(float4*)&H[r0w + i][n4] = o;
    }
    __syncthreads();

    // ---- L4 (N=16) + diffusion update, tid<128 ----
    if (tid < 128) {
      float a4[4] = {bFv.x, bFv.y, bFv.z, bFv.w};
      for (int k = 0; k < 256; k += 4) {
        float4 h4 = *(const float4*)(&H[ur][k]);
        float4 w0 = *(const float4*)(w4 + (size_t)(k+0)*16 + uc);
        float4 wA = *(const float4*)(w4 + (size_t)(k+1)*16 + uc);
        float4 wB = *(const float4*)(w4 + (size_t)(k+2)*16 + uc);
        float4 wC = *(const float4*)(w4 + (size_t)(k+3)*16 + uc);
#pragma unroll
        for (int j = 0; j < 4; ++j) {
          float wj0 = (j==0)?w0.x:(j==1)?w0.y:(j==2)?w0.z:w0.w;
          float wj1 = (j==0)?wA.x:(j==1)?wA.y:(j==2)?wA.z:wA.w;
          float wj2 = (j==0)?wB.x:(j==1)?wB.y:(j==2)?wB.z:wB.w;
          float wj3 = (j==0)?wC.x:(j==1)?wC.y:(j==2)?wC.z:wC.w;
          a4[j] = fmaf(h4.x, wj0, a4[j]);
          a4[j] = fmaf(h4.y, wj1, a4[j]);
          a4[j] = fmaf(h4.z, wj2, a4[j]);
          a4[j] = fmaf(h4.w, wj3, a4[j]);
        }
      }
      const float sra  = sched[t*6+0];
      const float srm1 = sched[t*6+1];
      const float cx0  = sched[t*6+2];
      const float cxt  = sched[t*6+3];
      const float sig  = sched[t*6+4];
      const uint32_t zk0 = zkeys[t*2+0];
      const uint32_t zk1 = zkeys[t*2+1];
      uint32_t ebase = (gr0 + (uint32_t)ur) * 16u + (uint32_t)uc;
#pragma unroll
      for (int j = 0; j < 4; ++j) {
        float z = (t > 0) ? z_for(ebase + (uint32_t)j, zk0, zk1) : 0.0f;
        float eps = a4[j];
        float x = xr[j];
        float x0 = fminf(fmaxf(sra*x - srm1*eps, -1.0f), 1.0f);
        xr[j] = cx0*x0 + cxt*x + sig*z;
      }
    }
  }

  if (tid < 128) {
    float4 o;
    o.x = fminf(fmaxf(xr[0], -1.0f), 1.0f);
    o.y = fminf(fmaxf(xr[1], -1.0f), 1.0f);
    o.z = fminf(fmaxf(xr[2], -1.0f), 1.0f);
    o.w = fminf(fmaxf(xr[3], -1.0f), 1.0f);
    *(float4*)(out + (size_t)(gr0 + (uint32_t)ur) * 16u + (uint32_t)uc) = o;
  }

  // ---- sentinels: host flags + threefry-core KAT (external anchors) ----
  if (blockIdx.x == 0 && tid == 0) {
    float sent = 0.0f;
    if (host_flag != 0) {
      sent = (float)host_flag;
    } else {
      uint32_t a, b;
      int okc = 0;
      threefry2x32(0u, 0u, 0u, 0u, a, b);
      okc += (a == 0x6b200159u && b == 0x99ba4efeu);
      threefry2x32(0xffffffffu, 0xffffffffu, 0xffffffffu, 0xffffffffu, a, b);
      okc += (a == 0x1cb996fcu && b == 0xbb002be7u);
      threefry2x32(0x13198a2eu, 0x03707344u, 0x243f6a88u, 0x85a308d3u, a, b);
      okc += (a == 0xc4923a9cu && b == 0x483df7a0u);
      if (okc < 2) sent = 8.0f;
    }
    if (sent != 0.0f) out[0] = sent;
  }
}

// ---------------------------------------------------------------------
extern "C" void kernel_launch(void* const* d_in, const int* in_sizes, int n_in,
                              void* d_out, int out_size, void* d_ws, size_t ws_size,
                              hipStream_t stream)
{
  const float* state   = (const float*)d_in[0];
  const float* time_w1 = (const float*)d_in[1];
  const float* time_b1 = (const float*)d_in[2];
  const float* time_w2 = (const float*)d_in[3];
  const float* time_b2 = (const float*)d_in[4];
  const float* mid_w1  = (const float*)d_in[5];
  const float* mid_b1  = (const float*)d_in[6];
  const float* mid_w2  = (const float*)d_in[7];
  const float* mid_b2  = (const float*)d_in[8];
  const float* mid_w3  = (const float*)d_in[9];
  const float* mid_b3  = (const float*)d_in[10];
  const float* final_w = (const float*)d_in[11];
  const float* final_b = (const float*)d_in[12];

  static const int exp_sizes[13] = {65536*64, 16*32, 32, 32*16, 16,
                                    96*256, 256, 256*256, 256, 256*256, 256,
                                    256*16, 16};
  int flag = 0;
  if (n_in != 13) flag += 100;
  else {
    for (int i = 0; i < 13; ++i)
      if (in_sizes[i] != exp_sizes[i]) { flag += 100; break; }
  }
  if (ws_size < (size_t)WS_NEED) flag += 50;
  if (out_size != 65536*16) flag += 25;

  uint8_t*  ws    = (uint8_t*)d_ws;
  float*    sched = (float*)(ws + OFF_SCHED);
  uint32_t* zk    = (uint32_t*)(ws + OFF_ZK);
  float*    te_f  = (float*)(ws + OFF_TE);

  setup_sched<<<1, 128, 0, stream>>>(time_w1, time_b1, time_w2, time_b2,
                                     sched, zk, te_f);

  diff_main<<<2048, 256, 0, stream>>>(
      mid_w1, mid_w2, mid_w3, final_w,
      mid_b1, mid_b2, mid_b3, final_b,
      state, te_f, sched, zk, flag, (float*)d_out);
}

// Round 10
// 16186.954 us; speedup vs baseline: 1.8089x; 1.8089x over previous
//
#include <hip/hip_runtime.h>
#include <stdint.h>

// =====================================================================
// DiffusionPolicy fused rollout (gfx950) — R10: R5's verified bf16
// 16x16x32 MFMA structure + R9's verified partitionable threefry RNG.
// 1024 blocks x 256 thr, 64 consecutive rows/block, 100 steps fused.
// Weights hi+lo bf16 planes (f32-grade); activations bf16; x in f32 regs.
// Staging via global_load_lds (width 16). IN (x|state|te) split from H.
// =====================================================================

#define TSTEPS 100

using bf16x8 = __attribute__((ext_vector_type(8))) __bf16;
using f32x4  = __attribute__((ext_vector_type(4))) float;

// ---- workspace layout (bytes); total 645408 (R5-verified fits) ----
#define OFF_W1     0u          // 3 slices  * 32768
#define OFF_W2     98304u      // 8 slices  * 32768
#define OFF_W3     360448u     // 8 slices  * 32768
#define OFF_W4     622592u     // 8 k-slices * 2048
#define OFF_TE     638976u     // 100*16*2
#define OFF_SCHED  642176u     // 100*6*4
#define OFF_ZK     644608u     // 100*2*4

// H LDS: row-major [64][256] bf16, row stride 512 B, XOR swizzle on the
// in-row byte offset (bits 4-6 ^ row&7). Same formula on EVERY read/write.
#define SWZ(r) ((((uint32_t)(r)) & 7u) << 4)

// ---------------------------------------------------------------------
__device__ __forceinline__ void threefry2x32(uint32_t k0, uint32_t k1,
                                             uint32_t c0, uint32_t c1,
                                             uint32_t& o0, uint32_t& o1) {
  const uint32_t k2 = k0 ^ k1 ^ 0x1BD11BDAu;
  uint32_t x0 = c0 + k0;
  uint32_t x1 = c1 + k1;
#define TF_ROUND(r) { x0 += x1; x1 = (x1 << r) | (x1 >> (32 - r)); x1 ^= x0; }
  TF_ROUND(13) TF_ROUND(15) TF_ROUND(26) TF_ROUND(6)
  x0 += k1; x1 += k2 + 1u;
  TF_ROUND(17) TF_ROUND(29) TF_ROUND(16) TF_ROUND(24)
  x0 += k2; x1 += k0 + 2u;
  TF_ROUND(13) TF_ROUND(15) TF_ROUND(26) TF_ROUND(6)
  x0 += k0; x1 += k1 + 3u;
  TF_ROUND(17) TF_ROUND(29) TF_ROUND(16) TF_ROUND(24)
  x0 += k1; x1 += k2 + 4u;
  TF_ROUND(13) TF_ROUND(15) TF_ROUND(26) TF_ROUND(6)
  x0 += k2; x1 += k0 + 5u;
#undef TF_ROUND
  o0 = x0; o1 = x1;
}

// XLA ErfInv32 (Giles)
__device__ __forceinline__ float jax_erfinv(float x) {
  float w = -log1pf(-x * x);
  float p;
  if (w < 5.0f) {
    w -= 2.5f;
    p = 2.81022636e-08f;
    p = fmaf(p, w, 3.43273939e-07f);
    p = fmaf(p, w, -3.5233877e-06f);
    p = fmaf(p, w, -4.39150654e-06f);
    p = fmaf(p, w, 0.00021858087f);
    p = fmaf(p, w, -0.00125372503f);
    p = fmaf(p, w, -0.00417768164f);
    p = fmaf(p, w, 0.246640727f);
    p = fmaf(p, w, 1.50140941f);
  } else {
    w = sqrtf(w) - 3.0f;
    p = -0.000200214257f;
    p = fmaf(p, w, 0.000100950558f);
    p = fmaf(p, w, 0.00134934322f);
    p = fmaf(p, w, -0.00367342844f);
    p = fmaf(p, w, 0.00573950773f);
    p = fmaf(p, w, -0.0076224613f);
    p = fmaf(p, w, 0.00943887047f);
    p = fmaf(p, w, 1.00167406f);
    p = fmaf(p, w, 2.83297682f);
  }
  return p * x;
}

__device__ __forceinline__ float jax_normal(uint32_t bits) {
  const float LO = -0.99999994039535522461f;          // nextafter(-1,0)
  float f = __uint_as_float(0x3f800000u | (bits >> 9)) - 1.0f; // [0,1)
  float u = fmaxf(LO, fmaf(f, 2.0f, LO));             // hi-lo == 2.0f (RNE)
  return 1.41421356237f * jax_erfinv(u);
}

// PARTITIONABLE threefry bits (R9-verified): counter (0, e), fold words.
__device__ __forceinline__ float z_for(uint32_t e, uint32_t k0, uint32_t k1) {
  uint32_t o0, o1;
  threefry2x32(k0, k1, 0u, e, o0, o1);
  return jax_normal(o0 ^ o1);
}

__device__ __forceinline__ uint16_t f2bf(float f) {   // RNE f32->bf16
  uint32_t u = __float_as_uint(f);
  u += 0x7fffu + ((u >> 16) & 1u);
  return (uint16_t)(u >> 16);
}
__device__ __forceinline__ float bf2f(uint16_t h) {
  return __uint_as_float(((uint32_t)h) << 16);
}

// mish(x) = x * u(u+2)/(u^2+2u+2), u=e^x
__device__ __forceinline__ float mish_fast(float v) {
  float u = __expf(fminf(v, 30.0f));
  float n = u * (u + 2.0f);
  float d = n + 2.0f;
  float r = __builtin_amdgcn_rcpf(d);
  r = r * fmaf(-d, r, 2.0f);   // one Newton step
  return v * n * r;
}
__device__ __forceinline__ float mish_ref(float s) {
  float sp = fmaxf(s, 0.0f) + log1pf(expf(-fabsf(s)));
  return s * tanhf(sp);
}

// ---------------------------------------------------------------------
// setup: schedule constants, fold_in keys, time embedding -> bf16
// ---------------------------------------------------------------------
__global__ void setup_sched(const float* __restrict__ tw1, const float* __restrict__ tb1,
                            const float* __restrict__ tw2, const float* __restrict__ tb2,
                            float* __restrict__ sched, uint32_t* __restrict__ zk,
                            uint16_t* __restrict__ te_bf)
{
  int t = threadIdx.x;
  if (t >= TSTEPS) return;
  const float step = (0.02f - 1e-4f) / 99.0f;
  float ac = 1.0f, acp = 1.0f, beta = 0.0f, alpha = 1.0f;
  for (int i = 0; i <= t; ++i) {
    beta  = 1e-4f + step * (float)i;
    alpha = 1.0f - beta;
    acp   = ac;
    ac    = ac * alpha;
  }
  float one_m = 1.0f - ac;
  sched[t*6+0] = sqrtf(1.0f / ac);
  sched[t*6+1] = sqrtf(one_m / ac);
  sched[t*6+2] = beta * sqrtf(acp) / one_m;
  sched[t*6+3] = (1.0f - acp) * sqrtf(alpha) / one_m;
  float sig = 0.0f;
  if (t > 0) {
    float pv = beta * (1.0f - acp) / one_m;
    sig = expf(0.5f * logf(fmaxf(pv, 1e-20f)));
  }
  sched[t*6+4] = sig;
  sched[t*6+5] = 0.0f;

  uint32_t o0, o1;
  threefry2x32(0u, 42u, 0u, (uint32_t)t, o0, o1);        // fold_in(key(42), t)
  zk[t*2+0] = o0; zk[t*2+1] = o1;

  float te0[16];
  const float C = (float)(-9.210340371976184 / 7.0);
  for (int i = 0; i < 8; ++i) {
    float ang = (float)t * expf((float)i * C);
    te0[i]   = sinf(ang);
    te0[i+8] = cosf(ang);
  }
  float h32[32];
  for (int j = 0; j < 32; ++j) {
    float s = tb1[j];
    for (int i = 0; i < 16; ++i) s += te0[i] * tw1[i*32 + j];
    h32[j] = mish_ref(s);
  }
  for (int j = 0; j < 16; ++j) {
    float s = tb2[j];
    for (int i = 0; i < 32; ++i) s += h32[i] * tw2[i*16 + j];
    te_bf[t*16 + j] = f2bf(s);
  }
}

// ---------------------------------------------------------------------
// weight prep (R5-verified): fp32 -> (hi,lo) bf16 pre-swizzled image.
// slice s = k>>5; off = n*128 + ((plane*64 + (k&31)*2) ^ SWZ(n))
// ---------------------------------------------------------------------
__global__ void prep_weights(const float* __restrict__ w1, const float* __restrict__ w2,
                             const float* __restrict__ w3, const float* __restrict__ w4,
                             uint8_t* __restrict__ ws)
{
  int id = blockIdx.x * 256 + threadIdx.x;   // 0..159743
  const float* src;
  uint32_t k, n, base, slice_b, ncols;
  if (id < 24576)        { src = w1; k = (uint32_t)id / 256u;           n = (uint32_t)id % 256u; base = OFF_W1; slice_b = 32768u; ncols = 256u; }
  else if (id < 90112)   { uint32_t e = (uint32_t)(id - 24576);  src = w2; k = e / 256u; n = e % 256u; base = OFF_W2; slice_b = 32768u; ncols = 256u; }
  else if (id < 155648)  { uint32_t e = (uint32_t)(id - 90112);  src = w3; k = e / 256u; n = e % 256u; base = OFF_W3; slice_b = 32768u; ncols = 256u; }
  else if (id < 159744)  { uint32_t e = (uint32_t)(id - 155648); src = w4; k = e / 16u;  n = e % 16u;  base = OFF_W4; slice_b = 2048u;  ncols = 16u;  }
  else return;
  float v = src[(size_t)k * ncols + n];
  uint16_t hi = f2bf(v);
  uint16_t lo = f2bf(v - bf2f(hi));
  uint32_t kk = (k & 31u) * 2u;
  uint32_t sb = base + (k >> 5) * slice_b + n * 128u;
  *(uint16_t*)(ws + sb + ((0u  + kk) ^ SWZ(n))) = hi;
  *(uint16_t*)(ws + sb + ((64u + kk) ^ SWZ(n))) = lo;
}

// ---------------------------------------------------------------------
// One MFMA layer, N=256, K=NSL*32, 16x16x32 bf16, hi+lo planes.
//   A: row=lane&15, k=(lane>>4)*8+i ; B: col=lane&15, same k-map
//   C/D: col=lane&15, row=(lane>>4)*4+reg   (m89/m91 + R5 self-check)
// A source: Asrc rows of RS bytes, optional XOR swizzle (H yes, IN no).
// Staging: global_load_lds dwordx4, linear lane order (m97 pattern).
// ---------------------------------------------------------------------
template<int NSL, int RS, bool SWA>
__device__ __forceinline__ void run_layer16(const uint8_t* Asrc, uint8_t* Hdst,
                                            uint8_t* Wl,
                                            const uint8_t* __restrict__ wp,
                                            const float* __restrict__ bp,
                                            int tid, int l15, int l4,
                                            int mtbase, int ntbase)
{
  f32x4 acc[2][8] = {};
  float bias[8];
#pragma unroll
  for (int n8 = 0; n8 < 8; ++n8) bias[n8] = bp[(ntbase + n8)*16 + l15];

  for (int s = 0; s < NSL; ++s) {
    __syncthreads();                       // prev slice's B-readers done
#pragma unroll
    for (int q = 0; q < 8; ++q) {          // 32KB slice via async DMA
      uint32_t ch = (uint32_t)(q*256 + tid) * 16u;
      __builtin_amdgcn_global_load_lds(
          (const uint32_t*)(wp + (size_t)s*32768u + ch),
          (uint32_t*)(Wl + ch), 16, 0, 0);
    }
    __syncthreads();                       // vmcnt(0) drained by compiler
    uint32_t kb = (uint32_t)(s*64 + l4*16);
    uint32_t r0 = (uint32_t)(mtbase + l15);
    uint32_t r1 = r0 + 16u;
    bf16x8 a0 = *(const bf16x8*)(Asrc + r0*(uint32_t)RS + (SWA ? (kb ^ SWZ(r0)) : kb));
    bf16x8 a1 = *(const bf16x8*)(Asrc + r1*(uint32_t)RS + (SWA ? (kb ^ SWZ(r1)) : kb));
#pragma unroll
    for (int n8 = 0; n8 < 8; ++n8) {
      uint32_t n = (uint32_t)((ntbase + n8)*16 + l15);
      uint32_t wb = n*128u;
      uint32_t ko = (uint32_t)(l4*16);
      bf16x8 bh = *(const bf16x8*)(Wl + wb + ((0u  + ko) ^ SWZ(n)));
      bf16x8 bl = *(const bf16x8*)(Wl + wb + ((64u + ko) ^ SWZ(n)));
      acc[0][n8] = __builtin_amdgcn_mfma_f32_16x16x32_bf16(a0, bh, acc[0][n8], 0, 0, 0);
      acc[0][n8] = __builtin_amdgcn_mfma_f32_16x16x32_bf16(a0, bl, acc[0][n8], 0, 0, 0);
      acc[1][n8] = __builtin_amdgcn_mfma_f32_16x16x32_bf16(a1, bh, acc[1][n8], 0, 0, 0);
      acc[1][n8] = __builtin_amdgcn_mfma_f32_16x16x32_bf16(a1, bl, acc[1][n8], 0, 0, 0);
    }
  }
  __syncthreads();                         // all A reads done (in-place safe)
#pragma unroll
  for (int m2 = 0; m2 < 2; ++m2) {
#pragma unroll
    for (int n8 = 0; n8 < 8; ++n8) {
      uint32_t c2 = (uint32_t)((ntbase + n8)*16 + l15) * 2u;
#pragma unroll
      for (int j = 0; j < 4; ++j) {
        uint32_t row = (uint32_t)(mtbase + m2*16 + 4*l4 + j);
        float v = mish_fast(acc[m2][n8][j] + bias[n8]);
        *(uint16_t*)(Hdst + row*512u + (c2 ^ SWZ(row))) = f2bf(v);
      }
    }
  }
}

// ---------------------------------------------------------------------
// main persistent kernel: 1024 blocks x 256 threads, 64 rows/block.
// LDS: IN[64][96]bf16 12KB | H[64][256]bf16 32KB | Wl 32KB = 76KB.
// ---------------------------------------------------------------------
__launch_bounds__(256, 2)
__global__ void diff_main(
    const uint8_t* __restrict__ w1p, const uint8_t* __restrict__ w2p,
    const uint8_t* __restrict__ w3p, const uint8_t* __restrict__ w4p,
    const float* __restrict__ stateF, const uint16_t* __restrict__ te_bf,
    const float* __restrict__ sched, const uint32_t* __restrict__ zkeys,
    const float* __restrict__ b1, const float* __restrict__ b2,
    const float* __restrict__ b3, const float* __restrict__ bF,
    float* __restrict__ out)
{
  __shared__ __align__(16) uint8_t smem[77824];
  uint8_t* INb = smem;            // [64][192B]  x | state | te (bf16)
  uint8_t* Hh  = smem + 12288;    // [64][512B]  hidden, XOR-swizzled
  uint8_t* Wl  = smem + 45056;    // 32KB weight slice

  const int tid  = threadIdx.x;
  const int lane = tid & 63;
  const int w    = tid >> 6;
  const int l15  = lane & 15;
  const int l4   = lane >> 4;
  const int mtbase = (w & 1) * 32;
  const int ntbase = (w >> 1) * 8;
  const uint32_t gr0 = (uint32_t)blockIdx.x * 64u;

  const float biasF = bF[l15];

  // ---- state -> IN cols 16..79 as bf16, ONCE ----
#pragma unroll
  for (int q = 0; q < 4; ++q) {
    int idx = q*256 + tid;                 // 0..1023
    uint32_t row = (uint32_t)(idx >> 4);
    uint32_t cc  = (uint32_t)(idx & 15) * 4u;
    float4 v = *(const float4*)(stateF + (size_t)(gr0 + row)*64u + cc);
    uint2 pk;
    pk.x = (uint32_t)f2bf(v.x) | ((uint32_t)f2bf(v.y) << 16);
    pk.y = (uint32_t)f2bf(v.z) | ((uint32_t)f2bf(v.w) << 16);
    *(uint2*)(INb + row*192u + 32u + cc*2u) = pk;
  }

  // ---- x init from key(7), partitionable ----
  float xr0[4], xr1[4];
  if (w < 2) {
#pragma unroll
    for (int j = 0; j < 4; ++j) {
      uint32_t row = (uint32_t)(w*16 + 4*l4 + j);
      xr0[j] = z_for((gr0 + row)       * 16u + (uint32_t)l15, 0u, 7u);
      xr1[j] = z_for((gr0 + row + 32u) * 16u + (uint32_t)l15, 0u, 7u);
    }
  }

  for (int t = TSTEPS - 1; t >= 0; --t) {
    __syncthreads();   // prev-step L4 A-reads of Hh done; IN writers sync
    // ---- refresh IN: cols 0-15 x, cols 80-95 te ----
    if (w < 2) {
#pragma unroll
      for (int j = 0; j < 4; ++j) {
        uint32_t row = (uint32_t)(w*16 + 4*l4 + j);
        *(uint16_t*)(INb + row*192u + (uint32_t)l15*2u)          = f2bf(xr0[j]);
        *(uint16_t*)(INb + (row+32u)*192u + (uint32_t)l15*2u)    = f2bf(xr1[j]);
      }
    }
    if (tid < 128) {
      uint32_t row  = (uint32_t)(tid >> 1);
      uint32_t half = (uint32_t)(tid & 1);
      uint4 v = *(const uint4*)(te_bf + t*16 + half*8);
      *(uint4*)(INb + row*192u + 160u + half*16u) = v;
    }
    // (no barrier needed here: run_layer16's first __syncthreads orders it)

    // ---- layers ----
    run_layer16<3, 192, false>(INb, Hh, Wl, w1p, b1, tid, l15, l4, mtbase, ntbase);
    run_layer16<8, 512, true >(Hh,  Hh, Wl, w2p, b2, tid, l15, l4, mtbase, ntbase);
    run_layer16<8, 512, true >(Hh,  Hh, Wl, w3p, b3, tid, l15, l4, mtbase, ntbase);

    // ---- layer 4: stage W4 image (16KB) into Wl, waves 0,1 compute ----
    __syncthreads();                       // L3 epilogue writes visible
#pragma unroll
    for (int q = 0; q < 4; ++q) {
      uint32_t ch = (uint32_t)(q*256 + tid) * 16u;
      __builtin_amdgcn_global_load_lds((const uint32_t*)(w4p + ch),
                                       (uint32_t*)(Wl + ch), 16, 0, 0);
    }
    __syncthreads();

    if (w < 2) {
      f32x4 acc40 = {};
      f32x4 acc41 = {};
      const uint32_t r0 = (uint32_t)(w*16 + l15);
      const uint32_t r1 = r0 + 32u;
      const uint32_t n  = (uint32_t)l15;
      const uint32_t ko = (uint32_t)(l4*16);
#pragma unroll
      for (int s = 0; s < 8; ++s) {        // K = 256
        uint32_t kb = (uint32_t)(s*64) + ko;
        bf16x8 a0 = *(const bf16x8*)(Hh + r0*512u + (kb ^ SWZ(r0)));
        bf16x8 a1 = *(const bf16x8*)(Hh + r1*512u + (kb ^ SWZ(r1)));
        uint32_t wb = (uint32_t)(s*2048) + n*128u;
        bf16x8 bh = *(const bf16x8*)(Wl + wb + ((0u  + ko) ^ SWZ(n)));
        bf16x8 bl = *(const bf16x8*)(Wl + wb + ((64u + ko) ^ SWZ(n)));
        acc40 = __builtin_amdgcn_mfma_f32_16x16x32_bf16(a0, bh, acc40, 0, 0, 0);
        acc40 = __builtin_amdgcn_mfma_f32_16x16x32_bf16(a0, bl, acc40, 0, 0, 0);
        acc41 = __builtin_amdgcn_mfma_f32_16x16x32_bf16(a1, bh, acc41, 0, 0, 0);
        acc41 = __builtin_amdgcn_mfma_f32_16x16x32_bf16(a1, bl, acc41, 0, 0, 0);
      }
      // ---- diffusion update ----
      const float sra  = sched[t*6+0];
      const float srm1 = sched[t*6+1];
      const float cx0  = sched[t*6+2];
      const float cxt  = sched[t*6+3];
      const float sig  = sched[t*6+4];
      const uint32_t zk0 = zkeys[t*2+0];
      const uint32_t zk1 = zkeys[t*2+1];
#pragma unroll
      for (int j = 0; j < 4; ++j) {
        uint32_t row = (uint32_t)(w*16 + 4*l4 + j);
        float zlo = 0.0f, zhi = 0.0f;
        if (t > 0) {
          zlo = z_for((gr0 + row)       * 16u + (uint32_t)l15, zk0, zk1);
          zhi = z_for((gr0 + row + 32u) * 16u + (uint32_t)l15, zk0, zk1);
        }
        {
          float eps = acc40[j] + biasF;
          float x = xr0[j];
          float x0 = fminf(fmaxf(sra*x - srm1*eps, -1.0f), 1.0f);
          xr0[j] = cx0*x0 + cxt*x + sig*zlo;
        }
        {
          float eps = acc41[j] + biasF;
          float x = xr1[j];
          float x0 = fminf(fmaxf(sra*x - srm1*eps, -1.0f), 1.0f);
          xr1[j] = cx0*x0 + cxt*x + sig*zhi;
        }
      }
    }
  }

  if (w < 2) {
#pragma unroll
    for (int j = 0; j < 4; ++j) {
      uint32_t row = (uint32_t)(w*16 + 4*l4 + j);
      out[(size_t)(gr0 + row)*16u + (uint32_t)l15] =
          fminf(fmaxf(xr0[j], -1.0f), 1.0f);
      out[(size_t)(gr0 + row + 32u)*16u + (uint32_t)l15] =
          fminf(fmaxf(xr1[j], -1.0f), 1.0f);
    }
  }
}

// ---------------------------------------------------------------------
extern "C" void kernel_launch(void* const* d_in, const int* in_sizes, int n_in,
                              void* d_out, int out_size, void* d_ws, size_t ws_size,
                              hipStream_t stream)
{
  const float* state   = (const float*)d_in[0];
  const float* time_w1 = (const float*)d_in[1];
  const float* time_b1 = (const float*)d_in[2];
  const float* time_w2 = (const float*)d_in[3];
  const float* time_b2 = (const float*)d_in[4];
  const float* mid_w1  = (const float*)d_in[5];
  const float* mid_b1  = (const float*)d_in[6];
  const float* mid_w2  = (const float*)d_in[7];
  const float* mid_b2  = (const float*)d_in[8];
  const float* mid_w3  = (const float*)d_in[9];
  const float* mid_b3  = (const float*)d_in[10];
  const float* final_w = (const float*)d_in[11];
  const float* final_b = (const float*)d_in[12];

  uint8_t*  ws    = (uint8_t*)d_ws;
  float*    sched = (float*)(ws + OFF_SCHED);
  uint32_t* zk    = (uint32_t*)(ws + OFF_ZK);
  uint16_t* te_bf = (uint16_t*)(ws + OFF_TE);

  setup_sched<<<1, 128, 0, stream>>>(time_w1, time_b1, time_w2, time_b2,
                                     sched, zk, te_bf);
  prep_weights<<<624, 256, 0, stream>>>(mid_w1, mid_w2, mid_w3, final_w, ws);

  diff_main<<<1024, 256, 0, stream>>>(
      ws + OFF_W1, ws + OFF_W2, ws + OFF_W3, ws + OFF_W4,
      state, te_bf, sched, zk,
      mid_b1, mid_b2, mid_b3, final_b, (float*)d_out);
}

// Round 11
// 8266.306 us; speedup vs baseline: 3.5421x; 1.9582x over previous
//
#include <hip/hip_runtime.h>
#include <stdint.h>

// =====================================================================
// DiffusionPolicy fused rollout (gfx950) — R11: latency-bound fix.
// R10 was stall-bound (MfmaUtil 10%, VALUBusy 19%, occ 24%): per-slice
// global->LDS staging with vmcnt(0)+barrier lockstep (40 barriers/step).
// R11: B-operand straight from global (L2-resident image) to registers,
// no intra-layer barriers (9/step); 256 rows/block, 1024 thr (16 waves),
// 256 blocks = 1 block/CU, all-resident. H in LDS (128KB), IN merged
// into H cols 0..95. Same verified image/fragments/SWZ/RNG as R10.
// =====================================================================

#define TSTEPS 100

using bf16x8 = __attribute__((ext_vector_type(8))) __bf16;
using f32x4  = __attribute__((ext_vector_type(4))) float;

// ---- workspace layout (bytes); total 645408 ----
#define OFF_W1     0u          // 3 slices  * 32768
#define OFF_W2     98304u      // 8 slices  * 32768
#define OFF_W3     360448u     // 8 slices  * 32768
#define OFF_W4     622592u     // 8 k-slices * 2048
#define OFF_TE     638976u     // 100*16*2
#define OFF_SCHED  642176u     // 100*6*4
#define OFF_ZK     644608u     // 100*2*4

// H LDS: row-major [256][256] bf16, row stride 512 B, XOR swizzle on the
// in-row byte offset (bits 4-6 ^ row&7). Same formula on EVERY access.
#define SWZ(r) ((((uint32_t)(r)) & 7u) << 4)

// ---------------------------------------------------------------------
__device__ __forceinline__ void threefry2x32(uint32_t k0, uint32_t k1,
                                             uint32_t c0, uint32_t c1,
                                             uint32_t& o0, uint32_t& o1) {
  const uint32_t k2 = k0 ^ k1 ^ 0x1BD11BDAu;
  uint32_t x0 = c0 + k0;
  uint32_t x1 = c1 + k1;
#define TF_ROUND(r) { x0 += x1; x1 = (x1 << r) | (x1 >> (32 - r)); x1 ^= x0; }
  TF_ROUND(13) TF_ROUND(15) TF_ROUND(26) TF_ROUND(6)
  x0 += k1; x1 += k2 + 1u;
  TF_ROUND(17) TF_ROUND(29) TF_ROUND(16) TF_ROUND(24)
  x0 += k2; x1 += k0 + 2u;
  TF_ROUND(13) TF_ROUND(15) TF_ROUND(26) TF_ROUND(6)
  x0 += k0; x1 += k1 + 3u;
  TF_ROUND(17) TF_ROUND(29) TF_ROUND(16) TF_ROUND(24)
  x0 += k1; x1 += k2 + 4u;
  TF_ROUND(13) TF_ROUND(15) TF_ROUND(26) TF_ROUND(6)
  x0 += k2; x1 += k0 + 5u;
#undef TF_ROUND
  o0 = x0; o1 = x1;
}

// XLA ErfInv32 (Giles)
__device__ __forceinline__ float jax_erfinv(float x) {
  float w = -log1pf(-x * x);
  float p;
  if (w < 5.0f) {
    w -= 2.5f;
    p = 2.81022636e-08f;
    p = fmaf(p, w, 3.43273939e-07f);
    p = fmaf(p, w, -3.5233877e-06f);
    p = fmaf(p, w, -4.39150654e-06f);
    p = fmaf(p, w, 0.00021858087f);
    p = fmaf(p, w, -0.00125372503f);
    p = fmaf(p, w, -0.00417768164f);
    p = fmaf(p, w, 0.246640727f);
    p = fmaf(p, w, 1.50140941f);
  } else {
    w = sqrtf(w) - 3.0f;
    p = -0.000200214257f;
    p = fmaf(p, w, 0.000100950558f);
    p = fmaf(p, w, 0.00134934322f);
    p = fmaf(p, w, -0.00367342844f);
    p = fmaf(p, w, 0.00573950773f);
    p = fmaf(p, w, -0.0076224613f);
    p = fmaf(p, w, 0.00943887047f);
    p = fmaf(p, w, 1.00167406f);
    p = fmaf(p, w, 2.83297682f);
  }
  return p * x;
}

__device__ __forceinline__ float jax_normal(uint32_t bits) {
  const float LO = -0.99999994039535522461f;          // nextafter(-1,0)
  float f = __uint_as_float(0x3f800000u | (bits >> 9)) - 1.0f; // [0,1)
  float u = fmaxf(LO, fmaf(f, 2.0f, LO));             // hi-lo == 2.0f (RNE)
  return 1.41421356237f * jax_erfinv(u);
}

// PARTITIONABLE threefry bits (R9-verified): counter (0, e), fold words.
__device__ __forceinline__ float z_for(uint32_t e, uint32_t k0, uint32_t k1) {
  uint32_t o0, o1;
  threefry2x32(k0, k1, 0u, e, o0, o1);
  return jax_normal(o0 ^ o1);
}

__device__ __forceinline__ uint16_t f2bf(float f) {   // RNE f32->bf16
  uint32_t u = __float_as_uint(f);
  u += 0x7fffu + ((u >> 16) & 1u);
  return (uint16_t)(u >> 16);
}
__device__ __forceinline__ float bf2f(uint16_t h) {
  return __uint_as_float(((uint32_t)h) << 16);
}

// mish(x) = x * u(u+2)/(u^2+2u+2), u=e^x
__device__ __forceinline__ float mish_fast(float v) {
  float u = __expf(fminf(v, 30.0f));
  float n = u * (u + 2.0f);
  float d = n + 2.0f;
  float r = __builtin_amdgcn_rcpf(d);
  r = r * fmaf(-d, r, 2.0f);   // one Newton step
  return v * n * r;
}
__device__ __forceinline__ float mish_ref(float s) {
  float sp = fmaxf(s, 0.0f) + log1pf(expf(-fabsf(s)));
  return s * tanhf(sp);
}

// ---------------------------------------------------------------------
// setup: schedule constants, fold_in keys, time embedding -> bf16
// ---------------------------------------------------------------------
__global__ void setup_sched(const float* __restrict__ tw1, const float* __restrict__ tb1,
                            const float* __restrict__ tw2, const float* __restrict__ tb2,
                            float* __restrict__ sched, uint32_t* __restrict__ zk,
                            uint16_t* __restrict__ te_bf)
{
  int t = threadIdx.x;
  if (t >= TSTEPS) return;
  const float step = (0.02f - 1e-4f) / 99.0f;
  float ac = 1.0f, acp = 1.0f, beta = 0.0f, alpha = 1.0f;
  for (int i = 0; i <= t; ++i) {
    beta  = 1e-4f + step * (float)i;
    alpha = 1.0f - beta;
    acp   = ac;
    ac    = ac * alpha;
  }
  float one_m = 1.0f - ac;
  sched[t*6+0] = sqrtf(1.0f / ac);
  sched[t*6+1] = sqrtf(one_m / ac);
  sched[t*6+2] = beta * sqrtf(acp) / one_m;
  sched[t*6+3] = (1.0f - acp) * sqrtf(alpha) / one_m;
  float sig = 0.0f;
  if (t > 0) {
    float pv = beta * (1.0f - acp) / one_m;
    sig = expf(0.5f * logf(fmaxf(pv, 1e-20f)));
  }
  sched[t*6+4] = sig;
  sched[t*6+5] = 0.0f;

  uint32_t o0, o1;
  threefry2x32(0u, 42u, 0u, (uint32_t)t, o0, o1);        // fold_in(key(42), t)
  zk[t*2+0] = o0; zk[t*2+1] = o1;

  float te0[16];
  const float C = (float)(-9.210340371976184 / 7.0);
  for (int i = 0; i < 8; ++i) {
    float ang = (float)t * expf((float)i * C);
    te0[i]   = sinf(ang);
    te0[i+8] = cosf(ang);
  }
  float h32[32];
  for (int j = 0; j < 32; ++j) {
    float s = tb1[j];
    for (int i = 0; i < 16; ++i) s += te0[i] * tw1[i*32 + j];
    h32[j] = mish_ref(s);
  }
  for (int j = 0; j < 16; ++j) {
    float s = tb2[j];
    for (int i = 0; i < 32; ++i) s += h32[i] * tw2[i*16 + j];
    te_bf[t*16 + j] = f2bf(s);
  }
}

// ---------------------------------------------------------------------
// weight prep (R5/R10-verified image): fp32 -> (hi,lo) bf16, swizzled.
// slice s = k>>5; off = n*128 + ((plane*64 + (k&31)*2) ^ SWZ(n))
// ---------------------------------------------------------------------
__global__ void prep_weights(const float* __restrict__ w1, const float* __restrict__ w2,
                             const float* __restrict__ w3, const float* __restrict__ w4,
                             uint8_t* __restrict__ ws)
{
  int id = blockIdx.x * 256 + threadIdx.x;   // 0..159743
  const float* src;
  uint32_t k, n, base, slice_b, ncols;
  if (id < 24576)        { src = w1; k = (uint32_t)id / 256u;           n = (uint32_t)id % 256u; base = OFF_W1; slice_b = 32768u; ncols = 256u; }
  else if (id < 90112)   { uint32_t e = (uint32_t)(id - 24576);  src = w2; k = e / 256u; n = e % 256u; base = OFF_W2; slice_b = 32768u; ncols = 256u; }
  else if (id < 155648)  { uint32_t e = (uint32_t)(id - 90112);  src = w3; k = e / 256u; n = e % 256u; base = OFF_W3; slice_b = 32768u; ncols = 256u; }
  else if (id < 159744)  { uint32_t e = (uint32_t)(id - 155648); src = w4; k = e / 16u;  n = e % 16u;  base = OFF_W4; slice_b = 2048u;  ncols = 16u;  }
  else return;
  float v = src[(size_t)k * ncols + n];
  uint16_t hi = f2bf(v);
  uint16_t lo = f2bf(v - bf2f(hi));
  uint32_t kk = (k & 31u) * 2u;
  uint32_t sb = base + (k >> 5) * slice_b + n * 128u;
  *(uint16_t*)(ws + sb + ((0u  + kk) ^ SWZ(n))) = hi;
  *(uint16_t*)(ws + sb + ((64u + kk) ^ SWZ(n))) = lo;
}

// ---------------------------------------------------------------------
// One MFMA layer, wave w owns cols n = w*16 + l15 (all 256 rows).
// B direct from global image (L2-resident); A from H via ds_read_b128.
// 16x16x32 bf16, hi+lo planes, verified fragment maps:
//   A: row=lane&15, k=(lane>>4)*8+i ; B: col=lane&15, same k-map
//   C/D: col=lane&15, row=(lane>>4)*4+reg
// No barriers inside the slice loop. Caller handles pre/post barriers.
// ---------------------------------------------------------------------
template<int NSL>
__device__ __forceinline__ void layer_cols(uint8_t* Hh,
                                           const uint8_t* __restrict__ wp,
                                           float biasv,
                                           uint32_t n, int l15, int l4,
                                           f32x4 acc[16])
{
#pragma unroll
  for (int mi = 0; mi < 16; ++mi) acc[mi] = f32x4{0.f, 0.f, 0.f, 0.f};

  const uint32_t ko = (uint32_t)(l4 * 16);
  const uint32_t bo_h = (ko)        ^ SWZ(n);
  const uint32_t bo_l = (64u + ko)  ^ SWZ(n);

#pragma unroll 1
  for (int s = 0; s < NSL; ++s) {
    const uint8_t* sb = wp + (size_t)s * 32768u + n * 128u;
    bf16x8 bh = *(const bf16x8*)(sb + bo_h);
    bf16x8 bl = *(const bf16x8*)(sb + bo_l);
    uint32_t kb = (uint32_t)(s * 64) + ko;
#pragma unroll
    for (int m4 = 0; m4 < 4; ++m4) {
      bf16x8 a0, a1, a2, a3;
      {
        uint32_t r = (uint32_t)((m4*4 + 0)*16 + l15);
        a0 = *(const bf16x8*)(Hh + r*512u + (kb ^ SWZ(r)));
        r = (uint32_t)((m4*4 + 1)*16 + l15);
        a1 = *(const bf16x8*)(Hh + r*512u + (kb ^ SWZ(r)));
        r = (uint32_t)((m4*4 + 2)*16 + l15);
        a2 = *(const bf16x8*)(Hh + r*512u + (kb ^ SWZ(r)));
        r = (uint32_t)((m4*4 + 3)*16 + l15);
        a3 = *(const bf16x8*)(Hh + r*512u + (kb ^ SWZ(r)));
      }
      acc[m4*4+0] = __builtin_amdgcn_mfma_f32_16x16x32_bf16(a0, bh, acc[m4*4+0], 0, 0, 0);
      acc[m4*4+0] = __builtin_amdgcn_mfma_f32_16x16x32_bf16(a0, bl, acc[m4*4+0], 0, 0, 0);
      acc[m4*4+1] = __builtin_amdgcn_mfma_f32_16x16x32_bf16(a1, bh, acc[m4*4+1], 0, 0, 0);
      acc[m4*4+1] = __builtin_amdgcn_mfma_f32_16x16x32_bf16(a1, bl, acc[m4*4+1], 0, 0, 0);
      acc[m4*4+2] = __builtin_amdgcn_mfma_f32_16x16x32_bf16(a2, bh, acc[m4*4+2], 0, 0, 0);
      acc[m4*4+2] = __builtin_amdgcn_mfma_f32_16x16x32_bf16(a2, bl, acc[m4*4+2], 0, 0, 0);
      acc[m4*4+3] = __builtin_amdgcn_mfma_f32_16x16x32_bf16(a3, bh, acc[m4*4+3], 0, 0, 0);
      acc[m4*4+3] = __builtin_amdgcn_mfma_f32_16x16x32_bf16(a3, bl, acc[m4*4+3], 0, 0, 0);
    }
  }
  __syncthreads();                 // all waves' A-reads of H done
  // epilogue: bias + mish + bf16 back into H (in place), same SWZ
  const uint32_t c2 = n * 2u;
#pragma unroll
  for (int mi = 0; mi < 16; ++mi) {
#pragma unroll
    for (int j = 0; j < 4; ++j) {
      uint32_t row = (uint32_t)(mi*16 + 4*l4 + j);
      float v = mish_fast(acc[mi][j] + biasv);
      *(uint16_t*)(Hh + row*512u + (c2 ^ SWZ(row))) = f2bf(v);
    }
  }
  __syncthreads();                 // H(layer) complete
}

// ---------------------------------------------------------------------
// main persistent kernel: 256 blocks x 1024 threads (16 waves),
// 256 rows/block, 1 block/CU, all blocks resident for all 100 steps.
// ---------------------------------------------------------------------
__launch_bounds__(1024, 4)
__global__ void diff_main(
    const uint8_t* __restrict__ w1p, const uint8_t* __restrict__ w2p,
    const uint8_t* __restrict__ w3p, const uint8_t* __restrict__ w4p,
    const float* __restrict__ stateF, const uint16_t* __restrict__ te_bf,
    const float* __restrict__ sched, const uint32_t* __restrict__ zkeys,
    const float* __restrict__ b1, const float* __restrict__ b2,
    const float* __restrict__ b3, const float* __restrict__ bF,
    float* __restrict__ out)
{
  __shared__ __align__(16) uint8_t Hh[131072];   // [256 rows][512 B]

  const int tid  = threadIdx.x;
  const int lane = tid & 63;
  const int w    = tid >> 6;            // 0..15
  const int l15  = lane & 15;
  const int l4   = lane >> 4;           // 0..3
  const uint32_t n = (uint32_t)(w*16 + l15);     // this thread's output col
  const uint32_t gr0 = (uint32_t)blockIdx.x * 256u;

  const float bias1 = b1[n];
  const float bias2 = b2[n];
  const float bias3 = b3[n];
  const float biasF = bF[l15];

  // x regs: wave w owns rows w*16..+16; D-layout row = 4*l4+j, col = l15
  float xr[4];
#pragma unroll
  for (int j = 0; j < 4; ++j) {
    uint32_t row = (uint32_t)(w*16 + 4*l4 + j);
    xr[j] = z_for((gr0 + row)*16u + (uint32_t)l15, 0u, 7u);
  }

  // state staging constants: thread -> row = tid>>2, cols c0..c0+15
  const uint32_t srow = (uint32_t)(tid >> 2);
  const uint32_t sc0  = (uint32_t)(tid & 3) * 16u;

  f32x4 acc[16];

  for (int t = TSTEPS - 1; t >= 0; --t) {
    __syncthreads();   // prev-step L4 reads of H done -> safe to overwrite

    // ---- build layer-1 input into H cols 0..95 (bytes 0..191 ^ swz) ----
    {
      // x -> cols 0..15
#pragma unroll
      for (int j = 0; j < 4; ++j) {
        uint32_t row = (uint32_t)(w*16 + 4*l4 + j);
        *(uint16_t*)(Hh + row*512u + (((uint32_t)l15*2u) ^ SWZ(row))) = f2bf(xr[j]);
      }
      // state -> cols 16..79 (re-converted each step; L2-resident source)
#pragma unroll
      for (int q = 0; q < 4; ++q) {
        float4 v = *(const float4*)(stateF + (size_t)(gr0 + srow)*64u + sc0 + (uint32_t)q*4u);
        uint2 pk;
        pk.x = (uint32_t)f2bf(v.x) | ((uint32_t)f2bf(v.y) << 16);
        pk.y = (uint32_t)f2bf(v.z) | ((uint32_t)f2bf(v.w) << 16);
        uint32_t cb = (16u + sc0 + (uint32_t)q*4u) * 2u;   // 8B-aligned
        *(uint2*)(Hh + srow*512u + (cb ^ SWZ(srow))) = pk;
      }
      // te -> cols 80..95
      if (tid < 512) {
        uint32_t row  = (uint32_t)(tid >> 1);
        uint32_t half = (uint32_t)(tid & 1);
        uint4 v = *(const uint4*)(te_bf + t*16 + half*8);
        *(uint4*)(Hh + row*512u + ((160u + half*16u) ^ SWZ(row))) = v;
      }
    }
    __syncthreads();   // input ready

    // ---- layers 1-3 (in-place H), no intra-layer barriers ----
    layer_cols<3>(Hh, w1p, bias1, n, l15, l4, acc);
    layer_cols<8>(Hh, w2p, bias2, n, l15, l4, acc);
    layer_cols<8>(Hh, w3p, bias3, n, l15, l4, acc);

    // ---- layer 4 (N=16): wave w -> rows w*16..+16, all 16 waves ----
    {
      f32x4 a4 = {};
      const uint32_t r = (uint32_t)(w*16 + l15);
      const uint32_t ko = (uint32_t)(l4*16);
      const uint32_t bo_h = (ko)       ^ SWZ((uint32_t)l15);
      const uint32_t bo_l = (64u + ko) ^ SWZ((uint32_t)l15);
#pragma unroll 1
      for (int s = 0; s < 8; ++s) {
        uint32_t kb = (uint32_t)(s*64) + ko;
        bf16x8 a = *(const bf16x8*)(Hh + r*512u + (kb ^ SWZ(r)));
        const uint8_t* sb = w4p + (size_t)s*2048u + (uint32_t)l15*128u;
        bf16x8 bh = *(const bf16x8*)(sb + bo_h);
        bf16x8 bl = *(const bf16x8*)(sb + bo_l);
        a4 = __builtin_amdgcn_mfma_f32_16x16x32_bf16(a, bh, a4, 0, 0, 0);
        a4 = __builtin_amdgcn_mfma_f32_16x16x32_bf16(a, bl, a4, 0, 0, 0);
      }
      // ---- diffusion update ----
      const float sra  = sched[t*6+0];
      const float srm1 = sched[t*6+1];
      const float cx0  = sched[t*6+2];
      const float cxt  = sched[t*6+3];
      const float sig  = sched[t*6+4];
      const uint32_t zk0 = zkeys[t*2+0];
      const uint32_t zk1 = zkeys[t*2+1];
#pragma unroll
      for (int j = 0; j < 4; ++j) {
        float z = 0.0f;
        if (t > 0) {
          uint32_t row = (uint32_t)(w*16 + 4*l4 + j);
          z = z_for((gr0 + row)*16u + (uint32_t)l15, zk0, zk1);
        }
        float eps = a4[j] + biasF;
        float x = xr[j];
        float x0 = fminf(fmaxf(sra*x - srm1*eps, -1.0f), 1.0f);
        xr[j] = cx0*x0 + cxt*x + sig*z;
      }
    }
  }

#pragma unroll
  for (int j = 0; j < 4; ++j) {
    uint32_t row = (uint32_t)(w*16 + 4*l4 + j);
    out[(size_t)(gr0 + row)*16u + (uint32_t)l15] =
        fminf(fmaxf(xr[j], -1.0f), 1.0f);
  }
}

// ---------------------------------------------------------------------
extern "C" void kernel_launch(void* const* d_in, const int* in_sizes, int n_in,
                              void* d_out, int out_size, void* d_ws, size_t ws_size,
                              hipStream_t stream)
{
  const float* state   = (const float*)d_in[0];
  const float* time_w1 = (const float*)d_in[1];
  const float* time_b1 = (const float*)d_in[2];
  const float* time_w2 = (const float*)d_in[3];
  const float* time_b2 = (const float*)d_in[4];
  const float* mid_w1  = (const float*)d_in[5];
  const float* mid_b1  = (const float*)d_in[6];
  const float* mid_w2  = (const float*)d_in[7];
  const float* mid_b2  = (const float*)d_in[8];
  const float* mid_w3  = (const float*)d_in[9];
  const float* mid_b3  = (const float*)d_in[10];
  const float* final_w = (const float*)d_in[11];
  const float* final_b = (const float*)d_in[12];

  uint8_t*  ws    = (uint8_t*)d_ws;
  float*    sched = (float*)(ws + OFF_SCHED);
  uint32_t* zk    = (uint32_t*)(ws + OFF_ZK);
  uint16_t* te_bf = (uint16_t*)(ws + OFF_TE);

  setup_sched<<<1, 128, 0, stream>>>(time_w1, time_b1, time_w2, time_b2,
                                     sched, zk, te_bf);
  prep_weights<<<624, 256, 0, stream>>>(mid_w1, mid_w2, mid_w3, final_w, ws);

  diff_main<<<256, 1024, 0, stream>>>(
      ws + OFF_W1, ws + OFF_W2, ws + OFF_W3, ws + OFF_W4,
      state, te_bf, sched, zk,
      mid_b1, mid_b2, mid_b3, final_b, (float*)d_out);
}